// Round 17
// baseline (164.837 us; speedup 1.0000x reference)
//
#include <hip/hip_runtime.h>

typedef short bf16x8 __attribute__((ext_vector_type(8)));
typedef float f32x4 __attribute__((ext_vector_type(4)));
typedef unsigned int u32;
typedef unsigned short u16;

#define NIT 21
#define SMIN 1e-38f          // clamp only guards the ~e^-55-probability all-flush row
#define CSH  140.0f          // constant exponent shift: E = 2^(x*S - 140)
#define LDSCOL 136           // padded k-stride in u16 (272B, 16B-aligned)

static __device__ __forceinline__ u16 f2bf(float f) {   // RNE pack (validated r8/r14/r16)
    u32 u = __float_as_uint(f);
    u = (u + 0x7fffu + ((u >> 16) & 1u)) >> 16;
    return (u16)u;
}
static __device__ __forceinline__ float bf2f(u16 h) {
    return __uint_as_float(((u32)h) << 16);
}

// MFMA Sinkhorn (r16 loop, validated at 153us). One 256-thread block per
// 128x128 matrix; af (A-operand row fragments) in registers; B-operand col
// fragments read per-iteration from E^T in LDS; phases = chained
// v_mfma_f32_16x16x32_bf16; a/b vectors in 256B LDS.
// Round-17 (init fixes only):
//  (1) constant shift C=140 replaces the per-row max pass: one streaming
//      load->exp2->pack->write init, no 32-float buffer, no max shfls.
//      Scale cancels through a/b exactly like the row-max shift did.
//  (2) Ecm XOR-swizzle: u16 k-offset ^= ((n>>3)&3)<<4. On init writes the
//      key == lg, moving the 4 lg-groups to 4 disjoint bank octets (the old
//      pattern put all 64 lanes on 8 banks -> the 13.1M conflict counter).
//      Same involution applied on loop reads; low 3 bits untouched so b128
//      alignment and k-slot order are preserved.
__global__ void __attribute__((amdgpu_flat_work_group_size(256, 256),
                               amdgpu_waves_per_eu(4, 4)))
sinkhorn_kernel(const float* __restrict__ in, float* __restrict__ out) {
    const int t  = threadIdx.x;
    const int w  = t >> 6;         // wave 0..3
    const int lg = (t >> 4) & 3;   // k-group within wave
    const int ln = t & 15;         // m/n within tile
    const size_t mat = (size_t)blockIdx.x << 14;
    const float S = 36.067376022224085f;   // (1/0.04)*log2(e)

    __shared__ __align__(16) u16 Ecm[128 * LDSCOL];   // E^T, k-swizzled per row
    __shared__ __align__(16) u16 a_lds[128];
    __shared__ __align__(16) u16 b_lds[128];

    bf16x8 af[2][4];   // af[th][c] = E[w*32+th*16+ln][c*32+lg*8 ..+7]

    // ---- init: streaming exp2 with constant shift; af regs + swizzled E^T ----
#pragma unroll
    for (int th = 0; th < 2; ++th) {
        const int M = w * 32 + th * 16 + ln;
        const float* src = in + mat + (size_t)M * 128 + lg * 8;
        const int ms = M ^ (lg << 4);          // swizzled within-row u16 index (key==lg on writes)
        float s = 0.f;
#pragma unroll
        for (int c = 0; c < 4; ++c) {
            float4 f0 = *(const float4*)(src + c * 32);
            float4 f1 = *(const float4*)(src + c * 32 + 4);
            float e0 = __builtin_amdgcn_exp2f(fmaf(f0.x, S, -CSH));
            float e1 = __builtin_amdgcn_exp2f(fmaf(f0.y, S, -CSH));
            float e2 = __builtin_amdgcn_exp2f(fmaf(f0.z, S, -CSH));
            float e3 = __builtin_amdgcn_exp2f(fmaf(f0.w, S, -CSH));
            float e4 = __builtin_amdgcn_exp2f(fmaf(f1.x, S, -CSH));
            float e5 = __builtin_amdgcn_exp2f(fmaf(f1.y, S, -CSH));
            float e6 = __builtin_amdgcn_exp2f(fmaf(f1.z, S, -CSH));
            float e7 = __builtin_amdgcn_exp2f(fmaf(f1.w, S, -CSH));
            s += ((e0 + e1) + (e2 + e3)) + ((e4 + e5) + (e6 + e7));
            bf16x8 fr;
            fr[0] = (short)f2bf(e0); fr[1] = (short)f2bf(e1);
            fr[2] = (short)f2bf(e2); fr[3] = (short)f2bf(e3);
            fr[4] = (short)f2bf(e4); fr[5] = (short)f2bf(e5);
            fr[6] = (short)f2bf(e6); fr[7] = (short)f2bf(e7);
            af[th][c] = fr;
            const int nb = c * 32 + lg * 8;    // Ecm row base for this fragment
#pragma unroll
            for (int j = 0; j < 8; ++j)
                Ecm[(nb + j) * LDSCOL + ms] = (u16)fr[j];
        }
        s += __shfl_xor(s, 16);                // row M held by lanes {ln,+16,+32,+48}
        s += __shfl_xor(s, 32);
        if (lg == 0) a_lds[M] = f2bf(__builtin_amdgcn_rcpf(fmaxf(s, SMIN)));
    }
    __syncthreads();

    const f32x4 z4 = {0.f, 0.f, 0.f, 0.f};

#pragma unroll 1
    for (int it = 0; it < NIT; ++it) {
        // ---- col phase: colsum_n = sum_k a_k E_kn (A = a replicated; B from Ecm) ----
        f32x4 acc0 = z4, acc1 = z4;
        const int N0 = w * 32 + ln;
        const int k0s = ((N0 >> 3) & 3) << 4;         // swizzle key for row N0
        const int k1s = (((N0 + 16) >> 3) & 3) << 4;  // and row N0+16
#pragma unroll
        for (int c = 0; c < 4; ++c) {
            const int kb = c * 32 + lg * 8;
            bf16x8 aop = *(const bf16x8*)&a_lds[kb];
            bf16x8 b0  = *(const bf16x8*)&Ecm[N0 * LDSCOL + (kb ^ k0s)];
            bf16x8 b1  = *(const bf16x8*)&Ecm[(N0 + 16) * LDSCOL + (kb ^ k1s)];
            acc0 = __builtin_amdgcn_mfma_f32_16x16x32_bf16(aop, b0, acc0, 0, 0, 0);
            acc1 = __builtin_amdgcn_mfma_f32_16x16x32_bf16(aop, b1, acc1, 0, 0, 0);
        }
        if (lg == 0) {   // D rows identical; lane holds col n=ln of its tile (m89 layout)
            b_lds[w * 32 + ln]      = f2bf(__builtin_amdgcn_rcpf(fmaxf(acc0[0], SMIN)));
            b_lds[w * 32 + 16 + ln] = f2bf(__builtin_amdgcn_rcpf(fmaxf(acc1[0], SMIN)));
        }
        __syncthreads();

        // ---- row phase: rowsum_m = sum_k E_mk b_k  (B = b replicated) ----
        if (it < NIT - 1) {
            f32x4 r0 = z4, r1 = z4;
#pragma unroll
            for (int c = 0; c < 4; ++c) {
                bf16x8 bop = *(const bf16x8*)&b_lds[c * 32 + lg * 8];
                r0 = __builtin_amdgcn_mfma_f32_16x16x32_bf16(af[0][c], bop, r0, 0, 0, 0);
                r1 = __builtin_amdgcn_mfma_f32_16x16x32_bf16(af[1][c], bop, r1, 0, 0, 0);
            }
            if (ln == 0) {   // D cols identical; lane holds rows lg*4+reg
#pragma unroll
                for (int r = 0; r < 4; ++r) {
                    a_lds[w * 32 +      lg * 4 + r] = f2bf(__builtin_amdgcn_rcpf(fmaxf(r0[r], SMIN)));
                    a_lds[w * 32 + 16 + lg * 4 + r] = f2bf(__builtin_amdgcn_rcpf(fmaxf(r1[r], SMIN)));
                }
            }
            __syncthreads();
        }
    }

    // ---- epilogue: out = E * a_m * b_n ----
#pragma unroll
    for (int th = 0; th < 2; ++th) {
        const int M = w * 32 + th * 16 + ln;
        float* dst = out + mat + (size_t)M * 128 + lg * 8;
        const float av = bf2f(a_lds[M]);
#pragma unroll
        for (int c = 0; c < 4; ++c) {
            const bf16x8 e = af[th][c];
            const bf16x8 bop = *(const bf16x8*)&b_lds[c * 32 + lg * 8];
            float4 o0, o1;
            o0.x = bf2f((u16)e[0]) * av * bf2f((u16)bop[0]);
            o0.y = bf2f((u16)e[1]) * av * bf2f((u16)bop[1]);
            o0.z = bf2f((u16)e[2]) * av * bf2f((u16)bop[2]);
            o0.w = bf2f((u16)e[3]) * av * bf2f((u16)bop[3]);
            o1.x = bf2f((u16)e[4]) * av * bf2f((u16)bop[4]);
            o1.y = bf2f((u16)e[5]) * av * bf2f((u16)bop[5]);
            o1.z = bf2f((u16)e[6]) * av * bf2f((u16)bop[6]);
            o1.w = bf2f((u16)e[7]) * av * bf2f((u16)bop[7]);
            *(float4*)(dst + c * 32)     = o0;
            *(float4*)(dst + c * 32 + 4) = o1;
        }
    }
}

extern "C" void kernel_launch(void* const* d_in, const int* in_sizes, int n_in,
                              void* d_out, int out_size, void* d_ws, size_t ws_size,
                              hipStream_t stream) {
    (void)n_in; (void)d_ws; (void)ws_size; (void)out_size;
    const float* in  = (const float*)d_in[0];
    float*       out = (float*)d_out;
    const int n_mat = in_sizes[0] / (128 * 128);  // 4096
    sinkhorn_kernel<<<dim3(n_mat), dim3(256), 0, stream>>>(in, out);
}

// Round 18
// 150.547 us; speedup vs baseline: 1.0949x; 1.0949x over previous
//
#include <hip/hip_runtime.h>

typedef short bf16x8 __attribute__((ext_vector_type(8)));
typedef float f32x4 __attribute__((ext_vector_type(4)));
typedef unsigned int u32;
typedef unsigned short u16;

#define NIT 21
#define SMIN 1e-33f
#define LDSCOL 136   // padded k-stride in u16 (272B, 16B-aligned) — r16-proven

static __device__ __forceinline__ u16 f2bf(float f) {   // RNE pack (validated r8/r14/r16)
    u32 u = __float_as_uint(f);
    u = (u + 0x7fffu + ((u >> 16) & 1u)) >> 16;
    return (u16)u;
}
static __device__ __forceinline__ float bf2f(u16 h) {
    return __uint_as_float(((u32)h) << 16);
}

// MFMA Sinkhorn, r16 dataflow (153us validated) at 512 threads / 8 waves per
// 128x128 matrix. r16's limiter was residency: 256-thread blocks = 16 waves/CU
// with all pipes <40% busy. Here each wave owns ONE 16-row tile (af, A-operand
// in regs) and one 16-col tile (B-operand read per-iter from the E^T LDS image,
// byte-identical layout to r16); phases are 4 chained v_mfma_f32_16x16x32_bf16.
// LDS unchanged (35,328B -> 4 blocks/CU), waves double to 32/CU; loop-live regs
// ~45 so 8 waves/SIMD fits. Numerics identical to r16 (row-max shift, bf16 E,
// lazy rcp factors; both mfma operands share the (lane,slot)->k map so any HW
// k-permutation cancels; C/D layout per m89).
__global__ __launch_bounds__(512)
void sinkhorn_kernel(const float* __restrict__ in, float* __restrict__ out) {
    const int t  = threadIdx.x;
    const int w  = t >> 6;         // wave 0..7
    const int lg = (t >> 4) & 3;   // k-group within wave
    const int ln = t & 15;         // m/n within tile
    const int M  = w * 16 + ln;    // this lane's matrix row (and col-tile base n)
    const size_t mat = (size_t)blockIdx.x << 14;
    const float S = 36.067376022224085f;   // (1/0.04)*log2(e)

    __shared__ __align__(16) u16 Ecm[128 * LDSCOL];   // E^T: Ecm[n*LDSCOL+k] = E[k][n]
    __shared__ __align__(16) u16 a_lds[128];
    __shared__ __align__(16) u16 b_lds[128];

    bf16x8 af[4];   // af[c] = E[M][c*32+lg*8 ..+7]

    // ---- init: load, rowmax, E = bf16(2^((x-m)*S)); af regs + transposed LDS image ----
    {
        const float* src = in + mat + (size_t)M * 128 + lg * 8;
        float v[4][8];
        float m = -3.4e38f;
#pragma unroll
        for (int c = 0; c < 4; ++c) {
            float4 f0 = *(const float4*)(src + c * 32);
            float4 f1 = *(const float4*)(src + c * 32 + 4);
            v[c][0] = f0.x; v[c][1] = f0.y; v[c][2] = f0.z; v[c][3] = f0.w;
            v[c][4] = f1.x; v[c][5] = f1.y; v[c][6] = f1.z; v[c][7] = f1.w;
#pragma unroll
            for (int j = 0; j < 8; ++j) m = fmaxf(m, v[c][j]);
        }
        m = fmaxf(m, __shfl_xor(m, 16));   // row M held by lanes {ln,+16,+32,+48}
        m = fmaxf(m, __shfl_xor(m, 32));
        const float nms = -m * S;
        float s = 0.f;
#pragma unroll
        for (int c = 0; c < 4; ++c) {
            bf16x8 fr;
#pragma unroll
            for (int j = 0; j < 8; ++j) {
                float e = __builtin_amdgcn_exp2f(fmaf(v[c][j], S, nms));
                s += e;
                fr[j] = (short)f2bf(e);
            }
            af[c] = fr;
#pragma unroll
            for (int j = 0; j < 8; ++j)     // one-time transposed scalar writes
                Ecm[(c * 32 + lg * 8 + j) * LDSCOL + M] = (u16)fr[j];
        }
        s += __shfl_xor(s, 16);
        s += __shfl_xor(s, 32);
        if (lg == 0) a_lds[M] = f2bf(__builtin_amdgcn_rcpf(fmaxf(s, SMIN)));  // rowsum in [1,128]
    }
    __syncthreads();

    const f32x4 z4 = {0.f, 0.f, 0.f, 0.f};

#pragma unroll 1
    for (int it = 0; it < NIT; ++it) {
        // ---- col phase: colsum_n = sum_k a_k E_kn (A = a replicated; B from Ecm) ----
        f32x4 acc = z4;
#pragma unroll
        for (int c = 0; c < 4; ++c) {
            const int kb = c * 32 + lg * 8;
            bf16x8 aop = *(const bf16x8*)&a_lds[kb];
            bf16x8 bop = *(const bf16x8*)&Ecm[M * LDSCOL + kb];
            acc = __builtin_amdgcn_mfma_f32_16x16x32_bf16(aop, bop, acc, 0, 0, 0);
        }
        if (lg == 0)   // D rows identical; lane holds col n=ln of its tile (m89 layout)
            b_lds[M] = f2bf(__builtin_amdgcn_rcpf(fmaxf(acc[0], SMIN)));
        __syncthreads();

        // ---- row phase: rowsum_m = sum_k E_mk b_k  (B = b replicated) ----
        if (it < NIT - 1) {
            f32x4 r0 = z4;
#pragma unroll
            for (int c = 0; c < 4; ++c) {
                bf16x8 bop = *(const bf16x8*)&b_lds[c * 32 + lg * 8];
                r0 = __builtin_amdgcn_mfma_f32_16x16x32_bf16(af[c], bop, r0, 0, 0, 0);
            }
            if (ln == 0) {   // D cols identical; lane holds tile rows lg*4+r
#pragma unroll
                for (int r = 0; r < 4; ++r)
                    a_lds[w * 16 + lg * 4 + r] =
                        f2bf(__builtin_amdgcn_rcpf(fmaxf(r0[r], SMIN)));
            }
            __syncthreads();
        }
    }

    // ---- epilogue: out = E * a_m * b_n ----
    {
        float* dst = out + mat + (size_t)M * 128 + lg * 8;
        const float av = bf2f(a_lds[M]);
#pragma unroll
        for (int c = 0; c < 4; ++c) {
            const bf16x8 e = af[c];
            const bf16x8 bop = *(const bf16x8*)&b_lds[c * 32 + lg * 8];
            float4 o0, o1;
            o0.x = bf2f((u16)e[0]) * av * bf2f((u16)bop[0]);
            o0.y = bf2f((u16)e[1]) * av * bf2f((u16)bop[1]);
            o0.z = bf2f((u16)e[2]) * av * bf2f((u16)bop[2]);
            o0.w = bf2f((u16)e[3]) * av * bf2f((u16)bop[3]);
            o1.x = bf2f((u16)e[4]) * av * bf2f((u16)bop[4]);
            o1.y = bf2f((u16)e[5]) * av * bf2f((u16)bop[5]);
            o1.z = bf2f((u16)e[6]) * av * bf2f((u16)bop[6]);
            o1.w = bf2f((u16)e[7]) * av * bf2f((u16)bop[7]);
            *(float4*)(dst + c * 32)     = o0;
            *(float4*)(dst + c * 32 + 4) = o1;
        }
    }
}

extern "C" void kernel_launch(void* const* d_in, const int* in_sizes, int n_in,
                              void* d_out, int out_size, void* d_ws, size_t ws_size,
                              hipStream_t stream) {
    (void)n_in; (void)d_ws; (void)ws_size; (void)out_size;
    const float* in  = (const float*)d_in[0];
    float*       out = (float*)d_out;
    const int n_mat = in_sizes[0] / (128 * 128);  // 4096
    sinkhorn_kernel<<<dim3(n_mat), dim3(512), 0, stream>>>(in, out);
}